// Round 13
// baseline (932.311 us; speedup 1.0000x reference)
//
#include <hip/hip_runtime.h>
#include <math.h>
#include <stdint.h>

typedef unsigned short u16;
typedef float f32x4 __attribute__((ext_vector_type(4)));
typedef short bf16x8 __attribute__((ext_vector_type(8)));

#define NVIEW 6

// ---------- helpers ----------
__device__ __forceinline__ u16 f2bf(float f){
  unsigned u = __float_as_uint(f);
  u += 0x7FFFu + ((u >> 16) & 1u);
  return (u16)(u >> 16);
}
__device__ __forceinline__ float bf2f(u16 h){
  return __uint_as_float(((unsigned)h) << 16);
}
__device__ __forceinline__ float fsig(float x){
  x = fminf(fmaxf(x, -30.f), 30.f);
  return 1.0f / (1.0f + __expf(-x));
}
__device__ __forceinline__ float ftanh(float x){
  x = fminf(fmaxf(x, -15.f), 15.f);
  float e = __expf(2.0f * x);
  return (e - 1.0f) / (e + 1.0f);
}
__device__ __forceinline__ float gelu_exact(float v){
  float x  = v * 0.70710678118654752f;
  float ax = fabsf(x);
  float t  = 1.0f / fmaf(0.3275911f, ax, 1.0f);
  float p  = t * fmaf(t, fmaf(t, fmaf(t, fmaf(t, 1.061405429f, -1.453152027f),
                                      1.421413741f), -0.284496736f), 0.254829592f);
  float er = copysignf(1.0f - p * __expf(-ax * ax), x);
  return 0.5f * v * (1.0f + er);
}
__device__ __forceinline__ void gload16(const u16* g, u16* l){
  __builtin_amdgcn_global_load_lds((const __attribute__((address_space(1))) unsigned int*)g,
                                   (__attribute__((address_space(3))) unsigned int*)l,
                                   16, 0, 0);
}

// ---------- setup kernels ----------
__global__ void k_cvt(const float* __restrict__ in, u16* __restrict__ out, long n4){
  long i = (long)blockIdx.x * blockDim.x + threadIdx.x;
  long stride = (long)gridDim.x * blockDim.x;
  for (; i < n4; i += stride){
    const float4 v = ((const float4*)in)[i];
    ushort4 o;
    o.x = f2bf(v.x); o.y = f2bf(v.y); o.z = f2bf(v.z); o.w = f2bf(v.w);
    ((ushort4*)out)[i] = o;
  }
}

// Wl[l][4u+q][k] = (k<256 ? Wih[l][q*256+u][k] : Whh[l][q*256+u][k-256]) as bf16
__global__ void k_build_wl(const float* __restrict__ Wih, const float* __restrict__ Whh,
                           u16* __restrict__ Wl){
  int idx = blockIdx.x * 256 + threadIdx.x;
  int l   = idx >> 19;
  int rem = idx & 524287;
  int ro  = rem >> 9;
  int k   = rem & 511;
  int u = ro >> 2, q = ro & 3;
  int ri = q * 256 + u;
  float v = (k < 256) ? Wih[(l * 1024 + ri) * 256 + k]
                      : Whh[(l * 1024 + ri) * 256 + (k - 256)];
  Wl[idx] = f2bf(v);
}

__global__ void k_build_bias(const float* __restrict__ bih, const float* __restrict__ bhh,
                             float* __restrict__ biasL){
  int idx = blockIdx.x * 256 + threadIdx.x;
  if (idx < 3072){
    int l = idx >> 10; int ro = idx & 1023;
    int u = ro >> 2, q = ro & 3;
    int ri = q * 256 + u;
    biasL[idx] = bih[l * 1024 + ri] + bhh[l * 1024 + ri];
  }
}

// =====================================================================
// Deep-ring 128x128 GEMM (r7-proven) for G1/G2.
// =====================================================================
template<int EPI>
__global__ __launch_bounds__(256, 2)
void gemm_dr(const u16* __restrict__ A0, long sA0,
             const u16* __restrict__ Bm, long sB,
             int N, int K, int NBn,
             const float* __restrict__ bias,
             const float* __restrict__ resid,
             u16* __restrict__ outb)
{
  __shared__ __align__(16) u16 lA[5 * 4096];
  __shared__ __align__(16) u16 lB[5 * 4096];

  const int tid  = threadIdx.x;
  const int lane = tid & 63;
  const int wid  = tid >> 6;
  const int wm = wid >> 1, wn = wid & 1;
  const int l15 = lane & 15, lk = lane >> 4;

  const int nwg = gridDim.x;
  const int qx  = nwg >> 3;
  const int bb  = blockIdx.x;
  const int swz = (bb & 7) * qx + (bb >> 3);
  const long m0 = (long)(swz / NBn) * 128;
  const int  n0 = (swz % NBn) * 128;
  const int  NT = K >> 5;

  const int rA0 = tid >> 2;
  const int cA  = tid & 3;
  const int slog = (((rA0 & 1) << 2) | cA) ^ ((rA0 >> 1) & 7);
  const int srow = (rA0 & ~1) | (slog >> 2);
  const int scol = (slog & 3) << 3;
  const int ldst = rA0 * 32 + cA * 8;

  auto STAGE = [&](int slot, int t){
    const int kb = t << 5;
    const int so = slot * 4096;
    #pragma unroll
    for (int c = 0; c < 2; ++c){
      const int r  = c * 64 + srow;
      gload16(A0 + (m0 + r) * sA0 + (kb + scol), &lA[so + c * 2048 + ldst]);
    }
    #pragma unroll
    for (int c = 0; c < 2; ++c){
      const int r  = c * 64 + srow;
      gload16(Bm + (long)(n0 + r) * sB + (kb + scol), &lB[so + c * 2048 + ldst]);
    }
  };

  f32x4 acc[4][4];
  #pragma unroll
  for (int i = 0; i < 4; ++i)
    #pragma unroll
    for (int j = 0; j < 4; ++j)
      acc[i][j] = (f32x4){0.f, 0.f, 0.f, 0.f};

  const int spA = (((l15 & 1) << 2) | lk) ^ (l15 >> 1);
  const int rdA = (wm * 32 + (l15 >> 1)) * 64 + spA * 8;
  const int rdB = (wn * 32 + (l15 >> 1)) * 64 + spA * 8;

  auto COMPUTE = [&](int slot){
    const int so = slot * 4096;
    bf16x8 af[4], bq[4];
    #pragma unroll
    for (int mf = 0; mf < 4; ++mf)
      af[mf] = *(const bf16x8*)&lA[so + rdA + mf * 512];
    #pragma unroll
    for (int nf = 0; nf < 4; ++nf)
      bq[nf] = *(const bf16x8*)&lB[so + rdB + nf * 512];
    #pragma unroll
    for (int mf = 0; mf < 4; ++mf)
      #pragma unroll
      for (int nf = 0; nf < 4; ++nf)
        acc[mf][nf] = __builtin_amdgcn_mfma_f32_16x16x32_bf16(af[mf], bq[nf], acc[mf][nf], 0, 0, 0);
  };

  STAGE(0, 0); STAGE(1, 1); STAGE(2, 2); STAGE(3, 3);

  int sr = 0, sw = 4;
  for (int t = 0; t + 4 <= NT; ++t){
    asm volatile("s_waitcnt vmcnt(12)" ::: "memory");
    asm volatile("s_barrier" ::: "memory");
    if (t + 4 < NT){ STAGE(sw, t + 4); }
    COMPUTE(sr);
    sr = (sr == 4) ? 0 : sr + 1;
    sw = (sw == 4) ? 0 : sw + 1;
  }
  asm volatile("s_waitcnt vmcnt(8)" ::: "memory");
  asm volatile("s_barrier" ::: "memory");
  COMPUTE(sr); sr = (sr == 4) ? 0 : sr + 1;
  asm volatile("s_waitcnt vmcnt(4)" ::: "memory");
  asm volatile("s_barrier" ::: "memory");
  COMPUTE(sr); sr = (sr == 4) ? 0 : sr + 1;
  asm volatile("s_waitcnt vmcnt(0)" ::: "memory");
  asm volatile("s_barrier" ::: "memory");
  COMPUTE(sr);

  #pragma unroll
  for (int mf = 0; mf < 4; ++mf){
    #pragma unroll
    for (int nf = 0; nf < 4; ++nf){
      int  n    = n0 + wn * 64 + nf * 16 + l15;
      long mrow = m0 + wm * 64 + mf * 16 + lk * 4;
      float bz = bias[n];
      #pragma unroll
      for (int r = 0; r < 4; ++r){
        float v = acc[mf][nf][r] + bz;
        long off = (mrow + r) * N + n;
        if (EPI == 0) v = gelu_exact(v) + resid[off];
        outb[off] = f2bf(v);
      }
    }
  }
}

// =====================================================================
// Fused persistent LSTM v3: B (Wl) loaded GLOBAL->REGISTER (no LDS for B).
// 256 blocks x 512 thr (8 waves = 2/SIMD); block owns 32 batch rows.
// Wave wv owns 128 DISTINCT gates (gb = wv*128 of 1024 interleaved) for
// ALL 32 rows -> every Wl byte enters the CU exactly once per (l,t).
// acc[2][8] static (rule 20). K-ROTATION (r12-proven) spreads L2 lines.
// A/h in 16 KB LDS [32][512], 16B-slot XOR swizzle (s^(row&7)); h written
// in place by the cell; x re-staged per t. NO barriers in the K-loop.
// =====================================================================
__global__ __launch_bounds__(512, 2)
void k_lstm(const u16* __restrict__ X0, const u16* __restrict__ Wl,
            const float* __restrict__ biasL,
            u16* __restrict__ HA, u16* __restrict__ HB)
{
  __shared__ __align__(16) u16 lA[16384];      // [32 rows][512 k] swizzled

  const int tid  = threadIdx.x;
  const int lane = tid & 63;
  const int wv   = tid >> 6;            // 0..7 -> gate block
  const int l15  = lane & 15, lk = lane >> 4;
  const int axk  = l15 & 7;
  const int a    = lane & 3;
  const int qb   = lane & ~3;
  const long R   = (long)blockIdx.x * 32;
  const int rotk = (blockIdx.x >> 3) & 15;
  const int gb   = wv * 128;

  const int xr_ = tid >> 4;             // 0..31
  const int xcb = tid & 15;             // 0..15
  const int xk  = xr_ & 7;

  f32x4 acc[2][8];
  float cc[2][8];
  float bv[8];

  for (int l = 0; l < 3; ++l){
    const u16* xsrc = (l == 0) ? X0 : ((l == 1) ? HA : HB);
    u16* hdst = (l == 1) ? HB : HA;
    const u16* wbase = Wl + (long)l * 524288 + (long)(gb + l15) * 512 + lk * 8;
    #pragma unroll
    for (int nt = 0; nt < 8; ++nt){
      bv[nt] = biasL[l * 1024 + gb + nt * 16 + l15];
      cc[0][nt] = 0.f; cc[1][nt] = 0.f;
    }
    __syncthreads();                     // prev layer fully done
    {                                    // zero h-half (t=0: h=0)
      bf16x8 z = (bf16x8){0,0,0,0,0,0,0,0};
      #pragma unroll
      for (int j = 0; j < 2; ++j){
        const int s = xcb * 2 + j;
        *(bf16x8*)&lA[xr_ * 512 + (32 + (s ^ xk)) * 8] = z;
      }
    }
    for (int t = 0; t < 6; ++t){
      // ---- stage x_t into LDS x-half ----
      bf16x8 xv0, xv1;
      const u16* xp = xsrc + ((R + xr_) * 6 + t) * 256 + xcb * 16;
      xv0 = *(const bf16x8*)(xp);
      xv1 = *(const bf16x8*)(xp + 8);
      #pragma unroll
      for (int mt = 0; mt < 2; ++mt)
        #pragma unroll
        for (int nt = 0; nt < 8; ++nt)
          acc[mt][nt] = (f32x4){0.f, 0.f, 0.f, 0.f};
      {
        const int s0 = xcb * 2;
        *(bf16x8*)&lA[xr_ * 512 + (s0 ^ xk) * 8] = xv0;
        *(bf16x8*)&lA[xr_ * 512 + ((s0 + 1) ^ xk) * 8] = xv1;
      }
      __syncthreads();                   // x + h(t-1) visible to all waves

      // ---- K loop: 16 bodies, B global->reg ping-pong, no barriers ----
      bf16x8 bqA[8], bqB[8];
      auto LOADB = [&](bf16x8* bq, int j){
        const int ktc = (j + rotk) & 15;
        const u16* bp = wbase + ktc * 32;
        #pragma unroll
        for (int nt = 0; nt < 8; ++nt)
          bq[nt] = *(const bf16x8*)(bp + (long)nt * 8192);
      };
      auto READA = [&](bf16x8* af, int j){
        const int ktc = (j + rotk) & 15;
        #pragma unroll
        for (int mt = 0; mt < 2; ++mt)
          af[mt] = *(const bf16x8*)&lA[(mt * 16 + l15) * 512 + ((ktc * 4 + lk) ^ axk) * 8];
      };
      LOADB(bqA, 0);
      for (int jj = 0; jj < 8; ++jj){
        LOADB(bqB, 2 * jj + 1);
        {
          bf16x8 af[2]; READA(af, 2 * jj);
          __builtin_amdgcn_s_setprio(1);
          #pragma unroll
          for (int mt = 0; mt < 2; ++mt)
            #pragma unroll
            for (int nt = 0; nt < 8; ++nt)
              acc[mt][nt] = __builtin_amdgcn_mfma_f32_16x16x32_bf16(af[mt], bqA[nt], acc[mt][nt], 0, 0, 0);
          __builtin_amdgcn_s_setprio(0);
        }
        if (jj < 7) LOADB(bqA, 2 * jj + 2);
        {
          bf16x8 af[2]; READA(af, 2 * jj + 1);
          __builtin_amdgcn_s_setprio(1);
          #pragma unroll
          for (int mt = 0; mt < 2; ++mt)
            #pragma unroll
            for (int nt = 0; nt < 8; ++nt)
              acc[mt][nt] = __builtin_amdgcn_mfma_f32_16x16x32_bf16(af[mt], bqB[nt], acc[mt][nt], 0, 0, 0);
          __builtin_amdgcn_s_setprio(0);
        }
      }
      __syncthreads();                   // all waves' x/h reads done

      // ---- cell update (verified quad-transpose) + h -> LDS h-half ----
      #pragma unroll
      for (int mt = 0; mt < 2; ++mt)
        #pragma unroll
        for (int nt = 0; nt < 8; ++nt){
          const float bz = bv[nt];
          float v0 = acc[mt][nt][0] + bz;
          float v1 = acc[mt][nt][1] + bz;
          float v2 = acc[mt][nt][2] + bz;
          float v3 = acc[mt][nt][3] + bz;
          float s0 = (a == 0) ? v0 : (a == 1) ? v1 : (a == 2) ? v2 : v3;
          float s1 = (a == 0) ? v1 : (a == 1) ? v2 : (a == 2) ? v3 : v0;
          float s2 = (a == 0) ? v2 : (a == 1) ? v3 : (a == 2) ? v0 : v1;
          float s3 = (a == 0) ? v3 : (a == 1) ? v0 : (a == 2) ? v1 : v2;
          float r0 = s0;
          float r1 = __shfl(s1, qb + ((a + 3) & 3));
          float r2 = __shfl(s2, qb + ((a + 2) & 3));
          float r3 = __shfl(s3, qb + ((a + 1) & 3));
          float wi = (a == 0) ? r0 : (a == 1) ? r1 : (a == 2) ? r2 : r3;
          float wf = (a == 1) ? r0 : (a == 2) ? r1 : (a == 3) ? r2 : r3;
          float wg = (a == 2) ? r0 : (a == 3) ? r1 : (a == 0) ? r2 : r3;
          float wo = (a == 3) ? r0 : (a == 0) ? r1 : (a == 1) ? r2 : r3;
          const int rloc = mt * 16 + lk * 4 + a;
          const int u    = wv * 32 + nt * 4 + (l15 >> 2);
          float co = cc[mt][nt];
          float ii = fsig(wi), ff = fsig(wf), gg = ftanh(wg), oo = fsig(wo);
          float cn = ff * co + ii * gg;
          float hn = oo * ftanh(cn);
          cc[mt][nt] = cn;
          lA[rloc * 512 + (32 + ((u >> 3) ^ (rloc & 7))) * 8 + (u & 7)] = f2bf(hn);
        }
      __syncthreads();                   // h visible
      // bounce h -> global (next layer's x / final output)
      {
        const int s0 = xcb * 2;
        bf16x8 h0 = *(const bf16x8*)&lA[xr_ * 512 + (32 + (s0 ^ xk)) * 8];
        bf16x8 h1 = *(const bf16x8*)&lA[xr_ * 512 + (32 + ((s0 + 1) ^ xk)) * 8];
        *(bf16x8*)(hdst + ((R + xr_) * 6 + t) * 256 + xcb * 16) = h0;
        *(bf16x8*)(hdst + ((R + xr_) * 6 + t) * 256 + xcb * 16 + 8) = h1;
      }
    }
  }
}

// ---------- tail: viewport + score + mean ----------
__global__ void k_score(const u16* __restrict__ X3, const float* __restrict__ Wv,
                        const float* __restrict__ bv, const float* __restrict__ Ws,
                        const float* __restrict__ bs, float* __restrict__ score){
  int lane = threadIdx.x & 63;
  int bm = blockIdx.x * 4 + (threadIdx.x >> 6);
  const u16* row = X3 + (long)bm * (NVIEW * 256);
  float4 wv = *(const float4*)(Wv + lane * 4);
  float p = 0.f;
  #pragma unroll
  for (int n = 0; n < NVIEW; ++n){
    ushort4 xv = *(const ushort4*)(row + n * 256 + lane * 4);
    float d = bf2f(xv.x) * wv.x + bf2f(xv.y) * wv.y + bf2f(xv.z) * wv.z + bf2f(xv.w) * wv.w;
    p += Ws[n] * d;
  }
  #pragma unroll
  for (int off = 32; off; off >>= 1) p += __shfl_xor(p, off);
  if (lane == 0){
    float sw = Ws[0] + Ws[1] + Ws[2] + Ws[3] + Ws[4] + Ws[5];
    score[bm] = p + bv[0] * sw + bs[0];
  }
}

__global__ void k_mean(const float* __restrict__ score, float* __restrict__ out){
  __shared__ float red[256];
  int b = blockIdx.x, tid = threadIdx.x;
  red[tid] = score[b * 256 + tid];
  __syncthreads();
  for (int s = 128; s > 0; s >>= 1){
    if (tid < s) red[tid] += red[tid + s];
    __syncthreads();
  }
  if (tid == 0) out[b] = red[0] * (1.0f / 256.0f);
}

// ---------- launcher ----------
extern "C" void kernel_launch(void* const* d_in, const int* in_sizes, int n_in,
                              void* d_out, int out_size, void* d_ws, size_t ws_size,
                              hipStream_t stream){
  const float* swin = (const float*)d_in[0];
  const float* conv = (const float*)d_in[1];
  const float* Wc   = (const float*)d_in[2];
  const float* bc   = (const float*)d_in[3];
  const float* Win  = (const float*)d_in[4];
  const float* b_in = (const float*)d_in[5];
  const float* Wih  = (const float*)d_in[6];
  const float* Whh  = (const float*)d_in[7];
  const float* bih  = (const float*)d_in[8];
  const float* bhh  = (const float*)d_in[9];
  const float* Wv   = (const float*)d_in[10];
  const float* bv   = (const float*)d_in[11];
  const float* Ws   = (const float*)d_in[12];
  const float* bs   = (const float*)d_in[13];
  float* out = (float*)d_out;

  char* w = (char*)d_ws;
  u16*  convb = (u16*)(w);
  u16*  X0    = (u16*)(w);
  u16*  XA    = (u16*)(w + 25165824);
  u16*  XB    = (u16*)(w + 50331648);
  u16*  Y     = (u16*)(w + 100663296);
  u16*  Wcb   = (u16*)(w + 201326592);
  u16*  Winb  = (u16*)(w + 203423744);
  u16*  Wl    = (u16*)(w + 203948032);
  float* biasL= (float*)(w + 207093760);
  float* scoreb = (float*)(w + 207106560);

  k_cvt<<<4096, 256, 0, stream>>>(conv, convb, 49152L * 1024 / 4);
  k_cvt<<<512, 256, 0, stream>>>(Wc, Wcb, 1048576 / 4);
  k_cvt<<<128, 256, 0, stream>>>(Win, Winb, 262144 / 4);
  k_build_wl<<<6144, 256, 0, stream>>>(Wih, Whh, Wl);
  k_build_bias<<<12, 256, 0, stream>>>(bih, bhh, biasL);

  // G1: Y = bf16( gelu(conv @ Wc^T + bc) + swin )   [49152 x 1024], NBn=8
  gemm_dr<0><<<3072, 256, 0, stream>>>(
      convb, 1024L, Wcb, 1024L, 1024, 1024, 8, bc, swin, Y);

  // G2: X0 = bf16( Y @ Win^T + b_in )               [49152 x 256], NBn=2
  gemm_dr<1><<<768, 256, 0, stream>>>(
      Y, 1024L, Winb, 1024L, 256, 1024, 2, b_in, (const float*)nullptr, X0);

  // Fused persistent LSTM v3 (B global->reg, gates split across waves).
  k_lstm<<<256, 512, 0, stream>>>(X0, Wl, biasL, XA, XB);

  k_score<<<2048, 256, 0, stream>>>(XA, Wv, bv, Ws, bs, scoreb);
  k_mean<<<32, 256, 0, stream>>>(scoreb, out);
}